// Round 14
// baseline (138.754 us; speedup 1.0000x reference)
//
#include <hip/hip_runtime.h>
#include <math.h>

#define EPS 1e-8f

typedef __attribute__((ext_vector_type(8))) short bf16x8;
typedef __attribute__((ext_vector_type(4))) float f32x4;

__device__ __forceinline__ unsigned short f2bf(float f) {
    unsigned int u = __float_as_uint(f);
    unsigned int r = (u + 0x7fffu + ((u >> 16) & 1u)) >> 16;
    return (unsigned short)r;
}
__device__ __forceinline__ float bf2f(unsigned short h) {
    return __uint_as_float(((unsigned int)h) << 16);
}

// ---------------------------------------------------------------------------
// Prep (round-2 proven): normalize each patch vector, split into bf16 hi/lo,
// store in 16x16x32 MFMA fragment order:
//   off(img, tile t, kstep s, lane l, e) = (((img*16 + t)*2 + s)*64 + l)*8 + e
// holding X[img, patch = t*16 + (l&15), d = s*32 + (l>>4)*8 + e].
// Serves BOTH A- and B-operands of mfma_f32_16x16x32_bf16 for D = X * Y^T.
// ---------------------------------------------------------------------------
__global__ __launch_bounds__(256) void prep_kernel(
    const float* __restrict__ normal, const float* __restrict__ defect,
    unsigned short* __restrict__ fragN_hi, unsigned short* __restrict__ fragN_lo,
    unsigned short* __restrict__ fragD_hi, unsigned short* __restrict__ fragD_lo)
{
    const int gimg = blockIdx.x;          // 0..127
    const bool isN = gimg < 64;
    const int img  = isN ? gimg : gimg - 64;
    const float* src = isN ? normal : defect;
    unsigned short* dhi = isN ? fragN_hi : fragD_hi;
    unsigned short* dlo = isN ? fragN_lo : fragD_lo;

    const int patch = threadIdx.x;
    const float4* xp = (const float4*)(src + ((size_t)img * 256 + patch) * 64);
    float x[64];
    float ss = 0.f;
    #pragma unroll
    for (int k = 0; k < 16; ++k) {
        float4 v = xp[k];
        x[4*k+0] = v.x; x[4*k+1] = v.y; x[4*k+2] = v.z; x[4*k+3] = v.w;
        ss += v.x*v.x + v.y*v.y + v.z*v.z + v.w*v.w;
    }
    const float inv = 1.f / (sqrtf(ss) + EPS);

    const int t  = patch >> 4;
    const int ll = patch & 15;
    #pragma unroll
    for (int s = 0; s < 2; ++s) {
        #pragma unroll
        for (int g = 0; g < 4; ++g) {
            const size_t off = ((((size_t)img * 16 + t) * 2 + s) * 64 + (g * 16 + ll)) * 8;
            unsigned short h8[8], l8[8];
            #pragma unroll
            for (int e = 0; e < 8; ++e) {
                const float v = x[s*32 + g*8 + e] * inv;
                const unsigned short hb = f2bf(v);
                h8[e] = hb;
                l8[e] = f2bf(v - bf2f(hb));
            }
            *(uint4*)(dhi + off) = *(const uint4*)h8;
            *(uint4*)(dlo + off) = *(const uint4*)l8;
        }
    }
}

// ---------------------------------------------------------------------------
// Round-12 body (R8 equilibrium: sim 122 us), swizzle reverted, wrapped in a
// persistent grid-stride loop: 2048 blocks x ~3 pairs. Keeps resident blocks
// pinned at the VGPR cap (4/CU) instead of draining between 1.3-us dispatches
// (R13 showed OccupancyPercent 31% vs 50% allowed; memory proven off the
// critical path by the FETCH_SIZE natural experiment).
// Pair decode (per iteration):
//   p in [0,4096): nd pair (i = p>>6, j = p&63) -> row-max only.
//   p in [4096, 4096+2016): nn unordered pair {i<j}: S once;
//     row-max-mean -> sim[i][j], col-max-mean -> sim[j][i].
// 4 waves; wave w owns r-tiles {4w..4w+3}. B streams from L2, reg dbuf.
// ---------------------------------------------------------------------------
__global__ __launch_bounds__(256) void mfma_sim_kernel(
    const unsigned short* __restrict__ fragN_hi, const unsigned short* __restrict__ fragN_lo,
    const unsigned short* __restrict__ fragD_hi, const unsigned short* __restrict__ fragD_lo,
    float* __restrict__ sim)
{
    const int t = threadIdx.x;
    const int l = t & 63;
    const int w = t >> 6;

    __shared__ float cp[16][4][16];   // nn: [c-tile][wave][col] partial col-maxes
    __shared__ float wpart[4];
    __shared__ float csum[4];

    #pragma unroll 1
    for (int p = blockIdx.x; p < 6112; p += (int)gridDim.x) {

        int i, j;
        bool is_nd;
        if (p < 4096) {
            is_nd = true;
            i = p >> 6;
            j = p & 63;
        } else {
            is_nd = false;
            int kk = p - 4096;        // triangular decode: unordered pair {i<j}
            int ii = 0;
            while (kk >= 63 - ii) { kk -= 63 - ii; ++ii; }
            i = ii;
            j = ii + 1 + kk;
        }
        const unsigned short* bhi_base = is_nd ? fragD_hi : fragN_hi;
        const unsigned short* blo_base = is_nd ? fragD_lo : fragN_lo;

        // A-fragments for this wave's 4 row-tiles (hi/lo x 2 k-steps)
        bf16x8 ah[4][2], al[4][2];
        #pragma unroll
        for (int r = 0; r < 4; ++r) {
            #pragma unroll
            for (int s = 0; s < 2; ++s) {
                const size_t off = ((((size_t)i * 16 + (w*4 + r)) * 2 + s) * 64 + l) * 8;
                ah[r][s] = *(const bf16x8*)(fragN_hi + off);
                al[r][s] = *(const bf16x8*)(fragN_lo + off);
            }
        }

        f32x4 rowmax[4];
        #pragma unroll
        for (int r = 0; r < 4; ++r)
            rowmax[r] = (f32x4){-3e38f, -3e38f, -3e38f, -3e38f};

        const size_t jb = (size_t)j * 16;

        // one c-tile's compute: 4 r-tiles x 6 MFMAs, rowmax always; col-max
        // only for nn blocks (uniform branch; accs retained in registers)
        #define COMPUTE_TILE(CT, BH, BL) do {                                        \
            f32x4 accs[4];                                                           \
            _Pragma("unroll")                                                        \
            for (int r = 0; r < 4; ++r) {                                            \
                f32x4 acc = (f32x4){0.f, 0.f, 0.f, 0.f};                             \
                __builtin_amdgcn_s_setprio(1);                                       \
                _Pragma("unroll")                                                    \
                for (int s = 0; s < 2; ++s) {                                        \
                    acc = __builtin_amdgcn_mfma_f32_16x16x32_bf16(al[r][s], BH[s], acc, 0, 0, 0); \
                    acc = __builtin_amdgcn_mfma_f32_16x16x32_bf16(ah[r][s], BL[s], acc, 0, 0, 0); \
                    acc = __builtin_amdgcn_mfma_f32_16x16x32_bf16(ah[r][s], BH[s], acc, 0, 0, 0); \
                }                                                                    \
                __builtin_amdgcn_s_setprio(0);                                       \
                accs[r] = acc;                                                       \
                _Pragma("unroll")                                                    \
                for (int e = 0; e < 4; ++e)                                          \
                    rowmax[r][e] = fmaxf(rowmax[r][e], acc[e]);                      \
            }                                                                        \
            if (!is_nd) {                                                            \
                f32x4 m4 = (f32x4){-3e38f, -3e38f, -3e38f, -3e38f};                  \
                _Pragma("unroll")                                                    \
                for (int r = 0; r < 4; ++r)                                          \
                    _Pragma("unroll")                                                \
                    for (int e = 0; e < 4; ++e)                                      \
                        m4[e] = fmaxf(m4[e], accs[r][e]);                            \
                float cmv = fmaxf(fmaxf(m4[0], m4[1]), fmaxf(m4[2], m4[3]));         \
                cmv = fmaxf(cmv, __shfl_xor(cmv, 16));                               \
                cmv = fmaxf(cmv, __shfl_xor(cmv, 32));                               \
                if (l < 16) cp[CT][w][l] = cmv;                                      \
            }                                                                        \
        } while (0)

        // register double-buffer: prefetch next tile's B before current's MFMAs
        bf16x8 bh0[2], bl0[2], bh1[2], bl1[2];
        #pragma unroll
        for (int s = 0; s < 2; ++s) {
            const size_t off = (((jb + 0) * 2 + s) * 64 + l) * 8;
            bh0[s] = *(const bf16x8*)(bhi_base + off);
            bl0[s] = *(const bf16x8*)(blo_base + off);
        }

        #pragma unroll 1
        for (int c = 0; c < 16; c += 2) {
            #pragma unroll
            for (int s = 0; s < 2; ++s) {
                const size_t off = (((jb + c + 1) * 2 + s) * 64 + l) * 8;
                bh1[s] = *(const bf16x8*)(bhi_base + off);
                bl1[s] = *(const bf16x8*)(blo_base + off);
            }
            COMPUTE_TILE(c, bh0, bl0);
            if (c < 14) {
                #pragma unroll
                for (int s = 0; s < 2; ++s) {
                    const size_t off = (((jb + c + 2) * 2 + s) * 64 + l) * 8;
                    bh0[s] = *(const bf16x8*)(bhi_base + off);
                    bl0[s] = *(const bf16x8*)(blo_base + off);
                }
            }
            COMPUTE_TILE(c + 1, bh1, bl1);
        }
        #undef COMPUTE_TILE

        // ---- row-max-mean (sim(i,j)) ----
        // C layout: col = l&15, row = (l>>4)*4 + e. Row-max = reduce across
        // the 16 lanes sharing l>>4; each row-max duplicated 16x in the sum.
        float s_sum = 0.f;
        #pragma unroll
        for (int r = 0; r < 4; ++r) {
            #pragma unroll
            for (int e = 0; e < 4; ++e) {
                float v = rowmax[r][e];
                v = fmaxf(v, __shfl_xor(v, 1));
                v = fmaxf(v, __shfl_xor(v, 2));
                v = fmaxf(v, __shfl_xor(v, 4));
                v = fmaxf(v, __shfl_xor(v, 8));
                s_sum += v;
            }
        }
        #pragma unroll
        for (int off = 1; off < 64; off <<= 1)
            s_sum += __shfl_xor(s_sum, off);

        if (l == 0) wpart[w] = s_sum;
        __syncthreads();
        if (t == 0) {
            const float sim_v = (wpart[0] + wpart[1] + wpart[2] + wpart[3]) * (1.f / (16.f * 256.f));
            sim[(is_nd ? 4096 : 0) + i * 64 + j] = sim_v;
        }

        // ---- col-max-mean (sim(j,i)) for nn pairs ----
        if (!is_nd) {
            const int ct = t >> 4;
            const int cl = t & 15;
            float m = fmaxf(fmaxf(cp[ct][0][cl], cp[ct][1][cl]),
                            fmaxf(cp[ct][2][cl], cp[ct][3][cl]));
            #pragma unroll
            for (int off = 1; off < 64; off <<= 1)
                m += __shfl_xor(m, off);
            if (l == 0) csum[w] = m;
            __syncthreads();
            if (t == 0) {
                const float sim_v = (csum[0] + csum[1] + csum[2] + csum[3]) * (1.f / 256.f);
                sim[j * 64 + i] = sim_v;
            }
        }

        // cross-pair LDS safety: all reads of cp/wpart/csum complete before
        // the next iteration overwrites them.
        __syncthreads();
    }
}

// ---------------------------------------------------------------------------
// Fallback fp32 path (proven in round 1) if ws is too small for frag arrays.
// ---------------------------------------------------------------------------
__global__ __launch_bounds__(256) void sim_kernel_f32(
    const float* __restrict__ normal, const float* __restrict__ defect,
    float* __restrict__ sim)
{
    __shared__ float Bs[256 * 64];
    const int t = threadIdx.x;
    const int pair = blockIdx.x;
    const int i = pair >> 7;
    const int j2 = pair & 127;
    const bool is_nn = (j2 < 64);
    const int j = is_nn ? j2 : (j2 - 64);
    const float* bsrc = is_nn ? normal : defect;

    {
        const float4* bp = (const float4*)(bsrc + ((size_t)j * 256 + t) * 64);
        float4 bv[16];
        float ss = 0.f;
        #pragma unroll
        for (int k = 0; k < 16; ++k) {
            bv[k] = bp[k];
            ss += bv[k].x*bv[k].x + bv[k].y*bv[k].y + bv[k].z*bv[k].z + bv[k].w*bv[k].w;
        }
        const float inv = 1.f / (sqrtf(ss) + EPS);
        float4* bq = (float4*)&Bs[t * 64];
        #pragma unroll
        for (int k = 0; k < 16; ++k) {
            float4 v = bv[k];
            v.x *= inv; v.y *= inv; v.z *= inv; v.w *= inv;
            bq[k] = v;
        }
    }
    float a[64];
    {
        const float4* ap = (const float4*)(normal + ((size_t)i * 256 + t) * 64);
        float ss = 0.f;
        #pragma unroll
        for (int k = 0; k < 16; ++k) {
            float4 v = ap[k];
            a[4*k+0] = v.x; a[4*k+1] = v.y; a[4*k+2] = v.z; a[4*k+3] = v.w;
            ss += v.x*v.x + v.y*v.y + v.z*v.z + v.w*v.w;
        }
        const float inv = 1.f / (sqrtf(ss) + EPS);
        #pragma unroll
        for (int d = 0; d < 64; ++d) a[d] *= inv;
    }
    __syncthreads();
    float maxv = -1e30f;
    #pragma unroll 2
    for (int q = 0; q < 256; ++q) {
        const float4* bq = (const float4*)&Bs[q * 64];
        float acc0 = 0.f, acc1 = 0.f;
        #pragma unroll
        for (int k = 0; k < 8; ++k) {
            float4 b0 = bq[k];
            float4 b1 = bq[k + 8];
            acc0 += a[4*k+0]*b0.x + a[4*k+1]*b0.y + a[4*k+2]*b0.z + a[4*k+3]*b0.w;
            acc1 += a[4*(k+8)+0]*b1.x + a[4*(k+8)+1]*b1.y + a[4*(k+8)+2]*b1.z + a[4*(k+8)+3]*b1.w;
        }
        maxv = fmaxf(maxv, acc0 + acc1);
    }
    __syncthreads();
    float s = maxv;
    #pragma unroll
    for (int off = 32; off > 0; off >>= 1) s += __shfl_down(s, off);
    const int wid = t >> 6;
    if ((t & 63) == 0) Bs[wid] = s;
    __syncthreads();
    if (t == 0) {
        const float sim_v = (Bs[0] + Bs[1] + Bs[2] + Bs[3]) * (1.f / 256.f);
        sim[(is_nn ? 0 : 4096) + i * 64 + j] = sim_v;
    }
}

__global__ __launch_bounds__(256) void stats_kernel(const float* __restrict__ sim,
                                                    float* __restrict__ out)
{
    const int t = threadIdx.x;
    double snn = 0, qnn = 0, snd = 0, qnd = 0;
    for (int k = t; k < 4096; k += 256) {
        const int r = k >> 6, c = k & 63;
        const float vnn = sim[k];
        if (r != c) { snn += vnn; qnn += (double)vnn * vnn; }
        const float vnd = sim[4096 + k];
        snd += vnd; qnd += (double)vnd * vnd;
    }
    #pragma unroll
    for (int off = 32; off > 0; off >>= 1) {
        snn += __shfl_down(snn, off);
        qnn += __shfl_down(qnn, off);
        snd += __shfl_down(snd, off);
        qnd += __shfl_down(qnd, off);
    }
    __shared__ double red[4][4];
    const int wid = t >> 6;
    if ((t & 63) == 0) { red[0][wid] = snn; red[1][wid] = qnn; red[2][wid] = snd; red[3][wid] = qnd; }
    __syncthreads();
    if (t == 0) {
        const double SN = red[0][0] + red[0][1] + red[0][2] + red[0][3];
        const double QN = red[1][0] + red[1][1] + red[1][2] + red[1][3];
        const double SD = red[2][0] + red[2][1] + red[2][2] + red[2][3];
        const double QD = red[3][0] + red[3][1] + red[3][2] + red[3][3];
        const double cnt = 64.0 * 63.0;
        const double mu_nn = SN / cnt;
        double var_nn = (QN - cnt * mu_nn * mu_nn) / (cnt - 1.0);
        if (var_nn < 0) var_nn = 0;
        const double sig_nn = sqrt(var_nn);
        const double mu_nd = SD / 4096.0;
        double var_nd = (QD - 4096.0 * mu_nd * mu_nd) / 4095.0;
        if (var_nd < 0) var_nd = 0;
        const double sig_nd = sqrt(var_nd);
        const double sep = (mu_nn - mu_nd) / (sig_nn + sig_nd + 1e-8);
        out[0] = (float)(-sep);
    }
}

extern "C" void kernel_launch(void* const* d_in, const int* in_sizes, int n_in,
                              void* d_out, int out_size, void* d_ws, size_t ws_size,
                              hipStream_t stream) {
    const float* normal = (const float*)d_in[0];
    const float* defect = (const float*)d_in[1];
    float* out = (float*)d_out;

    const size_t FRAG = (size_t)64 * 16 * 2 * 64 * 8;         // shorts per array
    const size_t need = FRAG * 4 * sizeof(unsigned short) + 8192 * sizeof(float);

    if (ws_size >= need) {
        unsigned short* base = (unsigned short*)d_ws;
        unsigned short* fNh = base;
        unsigned short* fNl = base + FRAG;
        unsigned short* fDh = base + 2 * FRAG;
        unsigned short* fDl = base + 3 * FRAG;
        float* sim = (float*)(base + 4 * FRAG);

        prep_kernel<<<128, 256, 0, stream>>>(normal, defect, fNh, fNl, fDh, fDl);
        mfma_sim_kernel<<<2048, 256, 0, stream>>>(fNh, fNl, fDh, fDl, sim);
        stats_kernel<<<1, 256, 0, stream>>>(sim, out);
    } else {
        float* sim = (float*)d_ws;  // 32 KB
        sim_kernel_f32<<<8192, 256, 0, stream>>>(normal, defect, sim);
        stats_kernel<<<1, 256, 0, stream>>>(sim, out);
    }
}

// Round 15
// 134.870 us; speedup vs baseline: 1.0288x; 1.0288x over previous
//
#include <hip/hip_runtime.h>
#include <math.h>

#define EPS 1e-8f

typedef __attribute__((ext_vector_type(8))) short bf16x8;
typedef __attribute__((ext_vector_type(4))) float f32x4;

__device__ __forceinline__ unsigned short f2bf(float f) {
    unsigned int u = __float_as_uint(f);
    unsigned int r = (u + 0x7fffu + ((u >> 16) & 1u)) >> 16;
    return (unsigned short)r;
}
__device__ __forceinline__ float bf2f(unsigned short h) {
    return __uint_as_float(((unsigned int)h) << 16);
}

// ---------------------------------------------------------------------------
// Prep (round-2 proven): normalize each patch vector, split into bf16 hi/lo,
// store in 16x16x32 MFMA fragment order:
//   off(img, tile t, kstep s, lane l, e) = (((img*16 + t)*2 + s)*64 + l)*8 + e
// holding X[img, patch = t*16 + (l&15), d = s*32 + (l>>4)*8 + e].
// Serves BOTH A- and B-operands of mfma_f32_16x16x32_bf16 for D = X * Y^T.
// ---------------------------------------------------------------------------
__global__ __launch_bounds__(256) void prep_kernel(
    const float* __restrict__ normal, const float* __restrict__ defect,
    unsigned short* __restrict__ fragN_hi, unsigned short* __restrict__ fragN_lo,
    unsigned short* __restrict__ fragD_hi, unsigned short* __restrict__ fragD_lo)
{
    const int gimg = blockIdx.x;          // 0..127
    const bool isN = gimg < 64;
    const int img  = isN ? gimg : gimg - 64;
    const float* src = isN ? normal : defect;
    unsigned short* dhi = isN ? fragN_hi : fragD_hi;
    unsigned short* dlo = isN ? fragN_lo : fragD_lo;

    const int patch = threadIdx.x;
    const float4* xp = (const float4*)(src + ((size_t)img * 256 + patch) * 64);
    float x[64];
    float ss = 0.f;
    #pragma unroll
    for (int k = 0; k < 16; ++k) {
        float4 v = xp[k];
        x[4*k+0] = v.x; x[4*k+1] = v.y; x[4*k+2] = v.z; x[4*k+3] = v.w;
        ss += v.x*v.x + v.y*v.y + v.z*v.z + v.w*v.w;
    }
    const float inv = 1.f / (sqrtf(ss) + EPS);

    const int t  = patch >> 4;
    const int ll = patch & 15;
    #pragma unroll
    for (int s = 0; s < 2; ++s) {
        #pragma unroll
        for (int g = 0; g < 4; ++g) {
            const size_t off = ((((size_t)img * 16 + t) * 2 + s) * 64 + (g * 16 + ll)) * 8;
            unsigned short h8[8], l8[8];
            #pragma unroll
            for (int e = 0; e < 8; ++e) {
                const float v = x[s*32 + g*8 + e] * inv;
                const unsigned short hb = f2bf(v);
                h8[e] = hb;
                l8[e] = f2bf(v - bf2f(hb));
            }
            *(uint4*)(dhi + off) = *(const uint4*)h8;
            *(uint4*)(dlo + off) = *(const uint4*)l8;
        }
    }
}

// ---------------------------------------------------------------------------
// Round-12 kernel (best: sim 121.7 us / total 135.0 us) with ONE change:
// B-fragment addressing converted to pointer-bump + immediate offsets.
// Two pointers (hi/lo) advance by one constant add per 2-tile iteration;
// all 8 loads use compile-time offsets {0,1024,2048,3072} B. Removes the
// per-load 64-bit affine address recompute from the VALU-gated loop
// (VALUBusy 46% ~ 44 VALU/c-tile vs ~16 algorithmically required).
// Blocks:
//   b in [0,4096): nd pair (i = b>>6, j = b&63) -> row-max only.
//   b in [4096, 4096+2016): nn unordered pair {i<j}: S once;
//     row-max-mean -> sim[i][j], col-max-mean -> sim[j][i].
// 4 waves; wave w owns r-tiles {4w..4w+3}. B streams from L2, reg dbuf.
// ---------------------------------------------------------------------------
__global__ __launch_bounds__(256) void mfma_sim_kernel(
    const unsigned short* __restrict__ fragN_hi, const unsigned short* __restrict__ fragN_lo,
    const unsigned short* __restrict__ fragD_hi, const unsigned short* __restrict__ fragD_lo,
    float* __restrict__ sim)
{
    const int t = threadIdx.x;
    const int l = t & 63;
    const int w = t >> 6;
    const int b = blockIdx.x;

    int i, j;
    bool is_nd;
    if (b < 4096) {
        is_nd = true;
        i = b >> 6;
        j = b & 63;
    } else {
        is_nd = false;
        int kk = b - 4096;        // triangular decode: unordered pair {i<j}
        int ii = 0;
        while (kk >= 63 - ii) { kk -= 63 - ii; ++ii; }
        i = ii;
        j = ii + 1 + kk;
    }
    const unsigned short* bhi_base = is_nd ? fragD_hi : fragN_hi;
    const unsigned short* blo_base = is_nd ? fragD_lo : fragN_lo;

    __shared__ float cp[16][4][16];   // nn: [c-tile][wave][col] partial col-maxes
    __shared__ float wpart[4];
    __shared__ float csum[4];

    // A-fragments for this wave's 4 row-tiles (hi/lo x 2 k-steps)
    bf16x8 ah[4][2], al[4][2];
    #pragma unroll
    for (int r = 0; r < 4; ++r) {
        #pragma unroll
        for (int s = 0; s < 2; ++s) {
            const size_t off = ((((size_t)i * 16 + (w*4 + r)) * 2 + s) * 64 + l) * 8;
            ah[r][s] = *(const bf16x8*)(fragN_hi + off);
            al[r][s] = *(const bf16x8*)(fragN_lo + off);
        }
    }

    f32x4 rowmax[4];
    #pragma unroll
    for (int r = 0; r < 4; ++r)
        rowmax[r] = (f32x4){-3e38f, -3e38f, -3e38f, -3e38f};

    // B pointers: tile c, kstep s, lane l lives at
    //   base + (jb + c)*1024 + s*512 + l*8   (shorts; tile stride 2048 B)
    const size_t jb = (size_t)j * 16;
    const unsigned short* pH = bhi_base + jb * 1024 + (size_t)l * 8;
    const unsigned short* pL = blo_base + jb * 1024 + (size_t)l * 8;

    // one c-tile's compute: 4 r-tiles x 6 MFMAs, rowmax always; col-max only
    // for nn blocks (uniform branch; acc values retained in registers)
    #define COMPUTE_TILE(CT, BH, BL) do {                                        \
        f32x4 accs[4];                                                           \
        _Pragma("unroll")                                                        \
        for (int r = 0; r < 4; ++r) {                                            \
            f32x4 acc = (f32x4){0.f, 0.f, 0.f, 0.f};                             \
            __builtin_amdgcn_s_setprio(1);                                       \
            _Pragma("unroll")                                                    \
            for (int s = 0; s < 2; ++s) {                                        \
                acc = __builtin_amdgcn_mfma_f32_16x16x32_bf16(al[r][s], BH[s], acc, 0, 0, 0); \
                acc = __builtin_amdgcn_mfma_f32_16x16x32_bf16(ah[r][s], BL[s], acc, 0, 0, 0); \
                acc = __builtin_amdgcn_mfma_f32_16x16x32_bf16(ah[r][s], BH[s], acc, 0, 0, 0); \
            }                                                                    \
            __builtin_amdgcn_s_setprio(0);                                       \
            accs[r] = acc;                                                       \
            _Pragma("unroll")                                                    \
            for (int e = 0; e < 4; ++e)                                          \
                rowmax[r][e] = fmaxf(rowmax[r][e], acc[e]);                      \
        }                                                                        \
        if (!is_nd) {                                                            \
            f32x4 m4 = (f32x4){-3e38f, -3e38f, -3e38f, -3e38f};                  \
            _Pragma("unroll")                                                    \
            for (int r = 0; r < 4; ++r)                                          \
                _Pragma("unroll")                                                \
                for (int e = 0; e < 4; ++e)                                      \
                    m4[e] = fmaxf(m4[e], accs[r][e]);                            \
            float cmv = fmaxf(fmaxf(m4[0], m4[1]), fmaxf(m4[2], m4[3]));         \
            cmv = fmaxf(cmv, __shfl_xor(cmv, 16));                               \
            cmv = fmaxf(cmv, __shfl_xor(cmv, 32));                               \
            if (l < 16) cp[CT][w][l] = cmv;                                      \
        }                                                                        \
    } while (0)

    // register double-buffer; prologue loads tile 0 then pointers sit at tile 1
    bf16x8 bh0[2], bl0[2], bh1[2], bl1[2];
    bh0[0] = *(const bf16x8*)(pH + 0);
    bh0[1] = *(const bf16x8*)(pH + 512);
    bl0[0] = *(const bf16x8*)(pL + 0);
    bl0[1] = *(const bf16x8*)(pL + 512);
    pH += 1024;
    pL += 1024;

    #pragma unroll 1
    for (int c = 0; c < 16; c += 2) {
        // load tile c+1 (pointers at tile c+1; immediate offsets 0/1024 B)
        bh1[0] = *(const bf16x8*)(pH + 0);
        bh1[1] = *(const bf16x8*)(pH + 512);
        bl1[0] = *(const bf16x8*)(pL + 0);
        bl1[1] = *(const bf16x8*)(pL + 512);
        COMPUTE_TILE(c, bh0, bl0);
        // load tile c+2 (immediate offsets 2048/3072 B)
        if (c < 14) {
            bh0[0] = *(const bf16x8*)(pH + 1024);
            bh0[1] = *(const bf16x8*)(pH + 1536);
            bl0[0] = *(const bf16x8*)(pL + 1024);
            bl0[1] = *(const bf16x8*)(pL + 1536);
        }
        COMPUTE_TILE(c + 1, bh1, bl1);
        pH += 2048;           // advance 2 tiles: next iter's c+1
        pL += 2048;
    }
    #undef COMPUTE_TILE

    // ---- row-max-mean (sim(i,j)) ----
    // C layout: col = l&15, row = (l>>4)*4 + e. Row-max = reduce across the
    // 16 lanes sharing l>>4; each row-max then duplicated 16x in the sum.
    float s_sum = 0.f;
    #pragma unroll
    for (int r = 0; r < 4; ++r) {
        #pragma unroll
        for (int e = 0; e < 4; ++e) {
            float v = rowmax[r][e];
            v = fmaxf(v, __shfl_xor(v, 1));
            v = fmaxf(v, __shfl_xor(v, 2));
            v = fmaxf(v, __shfl_xor(v, 4));
            v = fmaxf(v, __shfl_xor(v, 8));
            s_sum += v;
        }
    }
    #pragma unroll
    for (int off = 1; off < 64; off <<= 1)
        s_sum += __shfl_xor(s_sum, off);

    if (l == 0) wpart[w] = s_sum;
    __syncthreads();
    if (t == 0) {
        const float sim_v = (wpart[0] + wpart[1] + wpart[2] + wpart[3]) * (1.f / (16.f * 256.f));
        sim[(is_nd ? 4096 : 0) + i * 64 + j] = sim_v;
    }

    // ---- col-max-mean (sim(j,i)) for nn pairs ----
    if (!is_nd) {
        const int ct = t >> 4;
        const int cl = t & 15;
        float m = fmaxf(fmaxf(cp[ct][0][cl], cp[ct][1][cl]),
                        fmaxf(cp[ct][2][cl], cp[ct][3][cl]));
        #pragma unroll
        for (int off = 1; off < 64; off <<= 1)
            m += __shfl_xor(m, off);
        if (l == 0) csum[w] = m;
        __syncthreads();
        if (t == 0) {
            const float sim_v = (csum[0] + csum[1] + csum[2] + csum[3]) * (1.f / 256.f);
            sim[j * 64 + i] = sim_v;
        }
    }
}

// ---------------------------------------------------------------------------
// Fallback fp32 path (proven in round 1) if ws is too small for frag arrays.
// ---------------------------------------------------------------------------
__global__ __launch_bounds__(256) void sim_kernel_f32(
    const float* __restrict__ normal, const float* __restrict__ defect,
    float* __restrict__ sim)
{
    __shared__ float Bs[256 * 64];
    const int t = threadIdx.x;
    const int pair = blockIdx.x;
    const int i = pair >> 7;
    const int j2 = pair & 127;
    const bool is_nn = (j2 < 64);
    const int j = is_nn ? j2 : (j2 - 64);
    const float* bsrc = is_nn ? normal : defect;

    {
        const float4* bp = (const float4*)(bsrc + ((size_t)j * 256 + t) * 64);
        float4 bv[16];
        float ss = 0.f;
        #pragma unroll
        for (int k = 0; k < 16; ++k) {
            bv[k] = bp[k];
            ss += bv[k].x*bv[k].x + bv[k].y*bv[k].y + bv[k].z*bv[k].z + bv[k].w*bv[k].w;
        }
        const float inv = 1.f / (sqrtf(ss) + EPS);
        float4* bq = (float4*)&Bs[t * 64];
        #pragma unroll
        for (int k = 0; k < 16; ++k) {
            float4 v = bv[k];
            v.x *= inv; v.y *= inv; v.z *= inv; v.w *= inv;
            bq[k] = v;
        }
    }
    float a[64];
    {
        const float4* ap = (const float4*)(normal + ((size_t)i * 256 + t) * 64);
        float ss = 0.f;
        #pragma unroll
        for (int k = 0; k < 16; ++k) {
            float4 v = ap[k];
            a[4*k+0] = v.x; a[4*k+1] = v.y; a[4*k+2] = v.z; a[4*k+3] = v.w;
            ss += v.x*v.x + v.y*v.y + v.z*v.z + v.w*v.w;
        }
        const float inv = 1.f / (sqrtf(ss) + EPS);
        #pragma unroll
        for (int d = 0; d < 64; ++d) a[d] *= inv;
    }
    __syncthreads();
    float maxv = -1e30f;
    #pragma unroll 2
    for (int q = 0; q < 256; ++q) {
        const float4* bq = (const float4*)&Bs[q * 64];
        float acc0 = 0.f, acc1 = 0.f;
        #pragma unroll
        for (int k = 0; k < 8; ++k) {
            float4 b0 = bq[k];
            float4 b1 = bq[k + 8];
            acc0 += a[4*k+0]*b0.x + a[4*k+1]*b0.y + a[4*k+2]*b0.z + a[4*k+3]*b0.w;
            acc1 += a[4*(k+8)+0]*b1.x + a[4*(k+8)+1]*b1.y + a[4*(k+8)+2]*b1.z + a[4*(k+8)+3]*b1.w;
        }
        maxv = fmaxf(maxv, acc0 + acc1);
    }
    __syncthreads();
    float s = maxv;
    #pragma unroll
    for (int off = 32; off > 0; off >>= 1) s += __shfl_down(s, off);
    const int wid = t >> 6;
    if ((t & 63) == 0) Bs[wid] = s;
    __syncthreads();
    if (t == 0) {
        const float sim_v = (Bs[0] + Bs[1] + Bs[2] + Bs[3]) * (1.f / 256.f);
        sim[(is_nn ? 0 : 4096) + i * 64 + j] = sim_v;
    }
}

__global__ __launch_bounds__(256) void stats_kernel(const float* __restrict__ sim,
                                                    float* __restrict__ out)
{
    const int t = threadIdx.x;
    double snn = 0, qnn = 0, snd = 0, qnd = 0;
    for (int k = t; k < 4096; k += 256) {
        const int r = k >> 6, c = k & 63;
        const float vnn = sim[k];
        if (r != c) { snn += vnn; qnn += (double)vnn * vnn; }
        const float vnd = sim[4096 + k];
        snd += vnd; qnd += (double)vnd * vnd;
    }
    #pragma unroll
    for (int off = 32; off > 0; off >>= 1) {
        snn += __shfl_down(snn, off);
        qnn += __shfl_down(qnn, off);
        snd += __shfl_down(snd, off);
        qnd += __shfl_down(qnd, off);
    }
    __shared__ double red[4][4];
    const int wid = t >> 6;
    if ((t & 63) == 0) { red[0][wid] = snn; red[1][wid] = qnn; red[2][wid] = snd; red[3][wid] = qnd; }
    __syncthreads();
    if (t == 0) {
        const double SN = red[0][0] + red[0][1] + red[0][2] + red[0][3];
        const double QN = red[1][0] + red[1][1] + red[1][2] + red[1][3];
        const double SD = red[2][0] + red[2][1] + red[2][2] + red[2][3];
        const double QD = red[3][0] + red[3][1] + red[3][2] + red[3][3];
        const double cnt = 64.0 * 63.0;
        const double mu_nn = SN / cnt;
        double var_nn = (QN - cnt * mu_nn * mu_nn) / (cnt - 1.0);
        if (var_nn < 0) var_nn = 0;
        const double sig_nn = sqrt(var_nn);
        const double mu_nd = SD / 4096.0;
        double var_nd = (QD - 4096.0 * mu_nd * mu_nd) / 4095.0;
        if (var_nd < 0) var_nd = 0;
        const double sig_nd = sqrt(var_nd);
        const double sep = (mu_nn - mu_nd) / (sig_nn + sig_nd + 1e-8);
        out[0] = (float)(-sep);
    }
}

extern "C" void kernel_launch(void* const* d_in, const int* in_sizes, int n_in,
                              void* d_out, int out_size, void* d_ws, size_t ws_size,
                              hipStream_t stream) {
    const float* normal = (const float*)d_in[0];
    const float* defect = (const float*)d_in[1];
    float* out = (float*)d_out;

    const size_t FRAG = (size_t)64 * 16 * 2 * 64 * 8;         // shorts per array
    const size_t need = FRAG * 4 * sizeof(unsigned short) + 8192 * sizeof(float);

    if (ws_size >= need) {
        unsigned short* base = (unsigned short*)d_ws;
        unsigned short* fNh = base;
        unsigned short* fNl = base + FRAG;
        unsigned short* fDh = base + 2 * FRAG;
        unsigned short* fDl = base + 3 * FRAG;
        float* sim = (float*)(base + 4 * FRAG);

        prep_kernel<<<128, 256, 0, stream>>>(normal, defect, fNh, fNl, fDh, fDl);
        mfma_sim_kernel<<<4096 + 2016, 256, 0, stream>>>(fNh, fNl, fDh, fDl, sim);
        stats_kernel<<<1, 256, 0, stream>>>(sim, out);
    } else {
        float* sim = (float*)d_ws;  // 32 KB
        sim_kernel_f32<<<8192, 256, 0, stream>>>(normal, defect, sim);
        stats_kernel<<<1, 256, 0, stream>>>(sim, out);
    }
}